// Round 5
// baseline (5460.669 us; speedup 1.0000x reference)
//
#include <hip/hip_runtime.h>
#include <hip/hip_bf16.h>

#define B_ 64
#define T_ 2048
#define DIN_ 128
#define H_ 256
#define DOUT_ 128

typedef __bf16 bf16x8 __attribute__((ext_vector_type(8)));
typedef unsigned short u16x8 __attribute__((ext_vector_type(8)));
typedef unsigned int u32x2 __attribute__((ext_vector_type(2)));
typedef unsigned int u32x4 __attribute__((ext_vector_type(4)));
typedef float f32x4 __attribute__((ext_vector_type(4)));

// Inline-asm MFMA reading A from AGPR in place (gfx950 unified file).
// Hazard discipline (LLVM's hazard recognizer can't see inside asm):
//  - FIRST of a chain embeds leading s_nops (VALU-write -> MFMA SrcC read: 2 waits).
//  - LAST of a chain embeds trailing s_nops (MFMA write -> VALU read: <=10 waits).
//  - middle MFMAs chain C->C on the same accumulator: 0 waits required.
#define MFMA_A_FIRST(acc, wgt, st) \
    asm volatile("s_nop 1\n\ts_nop 1\n\tv_mfma_f32_16x16x32_bf16 %0, %1, %2, %0" \
                 : "+v"(acc) : "a"(wgt), "v"(st))
#define MFMA_A_MID(acc, wgt, st) \
    asm volatile("v_mfma_f32_16x16x32_bf16 %0, %1, %2, %0" \
                 : "+v"(acc) : "a"(wgt), "v"(st))
#define MFMA_A_LAST(acc, wgt, st) \
    asm volatile("v_mfma_f32_16x16x32_bf16 %0, %1, %2, %0\n\ts_nop 7\n\ts_nop 1" \
                 : "+v"(acc) : "a"(wgt), "v"(st))

static __device__ __forceinline__ unsigned short f2bf(float f) {
    union { float f; unsigned u; } v; v.f = f;
    unsigned r = v.u + 0x7FFFu + ((v.u >> 16) & 1u);   // RNE
    return (unsigned short)(r >> 16);
}
static __device__ __forceinline__ unsigned cvt_pk_bf16(float lo, float hi) {
    unsigned r;
    asm("v_cvt_pk_bf16_f32 %0, %1, %2" : "=v"(r) : "v"(lo), "v"(hi));
    return r;
}
static __device__ __forceinline__ float bfbits_lo(unsigned w) {
    union { unsigned u; float f; } v; v.u = w << 16; return v.f;
}
static __device__ __forceinline__ float bfbits_hi(unsigned w) {
    union { unsigned u; float f; } v; v.u = w & 0xFFFF0000u; return v.f;
}
static __device__ __forceinline__ float tanh_fast(float x) {
    // tanh(x) = 1 - 2/(exp2(2*log2e*x)+1); branch-free, no clamp, no NaN
    float e = __builtin_amdgcn_exp2f(2.885390081777927f * x);
    float r = __builtin_amdgcn_rcpf(e + 1.0f);
    return __builtin_fmaf(-2.0f, r, 1.0f);
}
static __device__ __forceinline__ u32x4 ld8f_u32(const float* p) {
    float4 a = *(const float4*)p;
    float4 b = *(const float4*)(p + 4);
    u32x4 u;
    u[0] = cvt_pk_bf16(a.x, a.y);
    u[1] = cvt_pk_bf16(a.z, a.w);
    u[2] = cvt_pk_bf16(b.x, b.y);
    u[3] = cvt_pk_bf16(b.z, b.w);
    return u;
}
static __device__ __forceinline__ bf16x8 ld8f_bf(const float* p) {
    return __builtin_bit_cast(bf16x8, ld8f_u32(p));
}

// -------- kernel 1 (swapped): Pre0[t][b][n] = b0[n] + sum_k x[b][t][k]*Wx0[n][k]
__global__ __launch_bounds__(256) void k_pre(const float* __restrict__ x,
                                             const float* __restrict__ Wx0,
                                             const float* __restrict__ b0,
                                             unsigned short* __restrict__ Pre0) {
    const int t  = blockIdx.x;
    const int bc = blockIdx.y;
    const int w  = threadIdx.x >> 6;
    const int l  = threadIdx.x & 63;
    const int lr = l & 15, lg = l >> 4;

    bf16x8 af[4];
    const float* xrow = x + ((size_t)(bc * 16 + lr) * T_ + t) * DIN_ + lg * 8;
#pragma unroll
    for (int kk = 0; kk < 4; kk++) af[kk] = ld8f_bf(xrow + kk * 32);

    unsigned short* op = Pre0 + ((size_t)t * B_ + bc * 16 + lr) * H_;

#pragma unroll
    for (int i = 0; i < 4; i++) {
        const int n0 = (w + 4 * i) * 16;
        const float* wrow = Wx0 + (size_t)(n0 + lr) * DIN_ + lg * 8;
        bf16x8 bfr[4];
#pragma unroll
        for (int kk = 0; kk < 4; kk++) bfr[kk] = ld8f_bf(wrow + kk * 32);
        float4 bv = *(const float4*)&b0[n0 + lg * 4];
        f32x4 acc = { bv.x, bv.y, bv.z, bv.w };
#pragma unroll
        for (int kk = 0; kk < 4; kk++)
            acc = __builtin_amdgcn_mfma_f32_16x16x32_bf16(bfr[kk], af[kk], acc, 0, 0, 0);
        u32x2 pk;
        pk[0] = cvt_pk_bf16(acc[0], acc[1]);
        pk[1] = cvt_pk_bf16(acc[2], acc[3]);
        *(u32x2*)&op[n0 + lg * 4] = pk;
    }
}

// -------- kernel 2: sequential scan. 4 blocks x 16 batch; 4 waves x 64 n.
// Layer 0 weights (wh0f, 128 regs) in VGPR via intrinsics (AGPRs are full, so
// the compiler cannot bank them); layer 1 weights (wx1f+wh1f, 256 regs) pinned
// in AGPR via asm "a" constraints, read in place by MFMA -> no shuttling.
__global__ __launch_bounds__(256, 1) void k_scan(const float* __restrict__ h0in,
                                                 const float* __restrict__ Wh0,
                                                 const float* __restrict__ Wx1,
                                                 const float* __restrict__ Wh1,
                                                 const float* __restrict__ b1,
                                                 const unsigned short* __restrict__ Pre0,
                                                 unsigned short* __restrict__ H1) {
    const int m0  = blockIdx.x * 16;
    const int tid = threadIdx.x;
    const int w   = tid >> 6, l = tid & 63;
    const int lr  = l & 15, lg = l >> 4;
    const int n0  = w * 64;

    __shared__ __align__(16) unsigned short h0s[2][16][256];
    __shared__ __align__(16) unsigned short h1s[2][16][256];

    // layer-1 weights -> AGPR-bound values (exactly 256 AGPRs)
    u32x4 wx1f[4][8], wh1f[4][8];
    // layer-0 weights -> VGPRs (128)
    bf16x8 wh0f[4][8];
#pragma unroll
    for (int u = 0; u < 4; u++) {
        const int n = n0 + u * 16 + lr;
#pragma unroll
        for (int kk = 0; kk < 8; kk++) {
            const int k0 = kk * 32 + lg * 8;
            wx1f[u][kk] = ld8f_u32(Wx1 + (size_t)n * H_ + k0);
            wh1f[u][kk] = ld8f_u32(Wh1 + (size_t)n * H_ + k0);
            wh0f[u][kk] = ld8f_bf(Wh0 + (size_t)n * H_ + k0);
        }
    }
    float4 b1q[4];
#pragma unroll
    for (int u = 0; u < 4; u++) b1q[u] = *(const float4*)&b1[n0 + u * 16 + lg * 4];

    // init state (swizzled row-major [b][n], XOR on 8-u16 chunks)
    for (int i = tid; i < 16 * 256; i += 256) {
        int r = i >> 8, e = i & 255;
        int sw = (((e >> 3) ^ (r & 7)) << 3) | (e & 7);
        h0s[0][r][sw] = f2bf(h0in[(size_t)(m0 + r) * H_ + e]);
        h1s[0][r][sw] = f2bf(h0in[(size_t)(B_ + m0 + r) * H_ + e]);
    }

    // Pre0 / H1 per-lane pointers: (b = m0+lr, n = n0+u*16+lg*4 .. +3)
    const unsigned short* prep = Pre0 + (size_t)(m0 + lr) * H_ + n0 + lg * 4;
    unsigned short* h1p = H1 + (size_t)(m0 + lr) * H_ + n0 + lg * 4;
    u32x2 pv[4];
#pragma unroll
    for (int u = 0; u < 4; u++) pv[u] = *(const u32x2*)(prep + u * 16);
    prep += B_ * H_;

    __syncthreads();

    const int swm = lr & 7;
    int swr[4];
#pragma unroll
    for (int u = 0; u < 4; u++) {
        const int e = n0 + u * 16 + lg * 4;
        swr[u] = (((e >> 3) ^ swm) << 3) | (e & 7);
    }

    int cur = 0;
    for (int t = 0; t < T_; t++) {
        const int nxt = cur ^ 1;
        // ---- layer 0 (intrinsics; compiler manages hazards): h0n^T = Wh0.h0^T + Pre0^T
        f32x4 acc[4];
#pragma unroll
        for (int u = 0; u < 4; u++) {
            acc[u][0] = bfbits_lo(pv[u][0]); acc[u][1] = bfbits_hi(pv[u][0]);
            acc[u][2] = bfbits_lo(pv[u][1]); acc[u][3] = bfbits_hi(pv[u][1]);
        }
        // prefetch next step's Pre0 (tail over-read lands in H1 region, harmless)
#pragma unroll
        for (int u = 0; u < 4; u++) pv[u] = *(const u32x2*)(prep + u * 16);
        prep += B_ * H_;
#pragma unroll
        for (int kk = 0; kk < 8; kk++) {
            const int c = (((kk * 4 + lg) ^ swm) << 3);
            bf16x8 s = __builtin_bit_cast(bf16x8, *(const u16x8*)&h0s[cur][lr][c]);
#pragma unroll
            for (int u = 0; u < 4; u++)
                acc[u] = __builtin_amdgcn_mfma_f32_16x16x32_bf16(wh0f[u][kk], s, acc[u], 0, 0, 0);
        }
#pragma unroll
        for (int u = 0; u < 4; u++) {
            u32x2 pk;
            pk[0] = cvt_pk_bf16(tanh_fast(acc[u][0]), tanh_fast(acc[u][1]));
            pk[1] = cvt_pk_bf16(tanh_fast(acc[u][2]), tanh_fast(acc[u][3]));
            *(u32x2*)&h0s[nxt][lr][swr[u]] = pk;
        }

        __syncthreads();   // single barrier per step (other pairs ordered by next one)

        // ---- layer 1 (asm, A from AGPR): h1n^T = Wh1.h1^T + Wx1.h0n^T + b1
        f32x4 d[4];
#pragma unroll
        for (int u = 0; u < 4; u++) {
            d[u][0] = b1q[u].x; d[u][1] = b1q[u].y; d[u][2] = b1q[u].z; d[u][3] = b1q[u].w;
        }
#pragma unroll
        for (int kk = 0; kk < 8; kk++) {
            const int c = (((kk * 4 + lg) ^ swm) << 3);
            u32x4 s1 = *(const u32x4*)&h1s[cur][lr][c];
#pragma unroll
            for (int u = 0; u < 4; u++) {
                if (kk == 0) { MFMA_A_FIRST(d[u], wh1f[u][0], s1); }
                else         { MFMA_A_MID(d[u], wh1f[u][kk], s1); }
            }
            u32x4 s0 = *(const u32x4*)&h0s[nxt][lr][c];
#pragma unroll
            for (int u = 0; u < 4; u++) {
                if (kk == 7) { MFMA_A_LAST(d[u], wx1f[u][7], s0); }
                else         { MFMA_A_MID(d[u], wx1f[u][kk], s0); }
            }
        }
#pragma unroll
        for (int u = 0; u < 4; u++) {
            u32x2 pk;
            pk[0] = cvt_pk_bf16(tanh_fast(d[u][0]), tanh_fast(d[u][1]));
            pk[1] = cvt_pk_bf16(tanh_fast(d[u][2]), tanh_fast(d[u][3]));
            *(u32x2*)&h1s[nxt][lr][swr[u]] = pk;
            *(u32x2*)(h1p + u * 16) = pk;
        }
        h1p += B_ * H_;

        cur = nxt;
    }
}

// -------- kernel 3 (swapped): Y[b][t][d] = bout[d] + sum_k H1[t][b][k]*Wout[d][k]
__global__ __launch_bounds__(256) void k_out(const unsigned short* __restrict__ H1,
                                             const float* __restrict__ Wout,
                                             const float* __restrict__ bout,
                                             float* __restrict__ out) {
    const int t  = blockIdx.x;
    const int bc = blockIdx.y;
    const int w  = threadIdx.x >> 6;
    const int l  = threadIdx.x & 63;
    const int lr = l & 15, lg = l >> 4;

    bf16x8 af[8];
    const unsigned short* hrow = H1 + ((size_t)t * B_ + bc * 16 + lr) * H_ + lg * 8;
#pragma unroll
    for (int kk = 0; kk < 8; kk++)
        af[kk] = __builtin_bit_cast(bf16x8, *(const u16x8*)(hrow + kk * 32));

#pragma unroll
    for (int i = 0; i < 2; i++) {
        const int n0 = (w + 4 * i) * 16;
        const float* wrow = Wout + (size_t)(n0 + lr) * H_ + lg * 8;
        float4 bv = *(const float4*)&bout[n0 + lg * 4];
        f32x4 acc = { bv.x, bv.y, bv.z, bv.w };
#pragma unroll
        for (int kk = 0; kk < 8; kk++) {
            bf16x8 bfr = ld8f_bf(wrow + kk * 32);
            acc = __builtin_amdgcn_mfma_f32_16x16x32_bf16(bfr, af[kk], acc, 0, 0, 0);
        }
        *(f32x4*)&out[((size_t)(bc * 16 + lr) * T_ + t) * DOUT_ + n0 + lg * 4] = acc;
    }
}

extern "C" void kernel_launch(void* const* d_in, const int* in_sizes, int n_in,
                              void* d_out, int out_size, void* d_ws, size_t ws_size,
                              hipStream_t stream) {
    const float* x    = (const float*)d_in[0];
    const float* h0   = (const float*)d_in[1];
    const float* Wx0  = (const float*)d_in[2];
    const float* Wh0  = (const float*)d_in[3];
    const float* b0   = (const float*)d_in[4];
    const float* Wx1  = (const float*)d_in[5];
    const float* Wh1  = (const float*)d_in[6];
    const float* b1   = (const float*)d_in[7];
    const float* Wout = (const float*)d_in[8];
    const float* bout = (const float*)d_in[9];
    float* out = (float*)d_out;

    unsigned short* Pre0 = (unsigned short*)d_ws;
    unsigned short* H1   = Pre0 + (size_t)T_ * B_ * H_;

    k_pre<<<dim3(T_, B_ / 16), 256, 0, stream>>>(x, Wx0, b0, Pre0);
    k_scan<<<dim3(4), 256, 0, stream>>>(h0, Wh0, Wx1, Wh1, b1, Pre0, H1);
    k_out<<<dim3(T_, B_ / 16), 256, 0, stream>>>(H1, Wout, bout, out);
}

// Round 6
// 3328.839 us; speedup vs baseline: 1.6404x; 1.6404x over previous
//
#include <hip/hip_runtime.h>
#include <hip/hip_bf16.h>

#define B_ 64
#define T_ 2048
#define DIN_ 128
#define H_ 256
#define DOUT_ 128

typedef __bf16 bf16x8 __attribute__((ext_vector_type(8)));
typedef unsigned short u16x8 __attribute__((ext_vector_type(8)));
typedef unsigned int u32x2 __attribute__((ext_vector_type(2)));
typedef unsigned int u32x4 __attribute__((ext_vector_type(4)));
typedef float f32x4 __attribute__((ext_vector_type(4)));

// Inline-asm MFMA with weights forced into ARCH VGPRs ("v") -> the register
// allocator cannot bank them in AGPRs -> no v_accvgpr shuttling (R2's tax).
// Hazard discipline (validated in R5): FIRST of each accumulation chain embeds
// leading s_nops (VALU-write -> MFMA SrcC read needs 2 waits); chain middles
// need 0 waits (C->C chaining); the LAST op of each chain is the compiler
// intrinsic so LLVM inserts the MFMA-write -> VALU-read waits itself (and can
// fill them with useful instructions instead of nops).
#define MFMA_FIRST(acc, wgt, st) \
    asm volatile("s_nop 1\n\ts_nop 1\n\tv_mfma_f32_16x16x32_bf16 %0, %1, %2, %0" \
                 : "+v"(acc) : "v"(wgt), "v"(st))
#define MFMA_MID(acc, wgt, st) \
    asm volatile("v_mfma_f32_16x16x32_bf16 %0, %1, %2, %0" \
                 : "+v"(acc) : "v"(wgt), "v"(st))

static __device__ __forceinline__ unsigned short f2bf(float f) {
    union { float f; unsigned u; } v; v.f = f;
    unsigned r = v.u + 0x7FFFu + ((v.u >> 16) & 1u);   // RNE
    return (unsigned short)(r >> 16);
}
static __device__ __forceinline__ unsigned cvt_pk_bf16(float lo, float hi) {
    unsigned r;
    asm("v_cvt_pk_bf16_f32 %0, %1, %2" : "=v"(r) : "v"(lo), "v"(hi));
    return r;
}
static __device__ __forceinline__ float bfbits_lo(unsigned w) {
    union { unsigned u; float f; } v; v.u = w << 16; return v.f;
}
static __device__ __forceinline__ float bfbits_hi(unsigned w) {
    union { unsigned u; float f; } v; v.u = w & 0xFFFF0000u; return v.f;
}
static __device__ __forceinline__ float tanh_fast(float x) {
    // tanh(x) = 1 - 2/(exp2(2*log2e*x)+1); branch-free, no clamp, no NaN
    float e = __builtin_amdgcn_exp2f(2.885390081777927f * x);
    float r = __builtin_amdgcn_rcpf(e + 1.0f);
    return __builtin_fmaf(-2.0f, r, 1.0f);
}
static __device__ __forceinline__ bf16x8 ld8f_bf(const float* p) {
    float4 a = *(const float4*)p;
    float4 b = *(const float4*)(p + 4);
    u32x4 u;
    u[0] = cvt_pk_bf16(a.x, a.y);
    u[1] = cvt_pk_bf16(a.z, a.w);
    u[2] = cvt_pk_bf16(b.x, b.y);
    u[3] = cvt_pk_bf16(b.z, b.w);
    return __builtin_bit_cast(bf16x8, u);
}

// -------- kernel 1 (swapped): Pre0[t][b][n] = b0[n] + sum_k x[b][t][k]*Wx0[n][k]
__global__ __launch_bounds__(256) void k_pre(const float* __restrict__ x,
                                             const float* __restrict__ Wx0,
                                             const float* __restrict__ b0,
                                             unsigned short* __restrict__ Pre0) {
    const int t  = blockIdx.x;
    const int bc = blockIdx.y;
    const int w  = threadIdx.x >> 6;
    const int l  = threadIdx.x & 63;
    const int lr = l & 15, lg = l >> 4;

    bf16x8 af[4];
    const float* xrow = x + ((size_t)(bc * 16 + lr) * T_ + t) * DIN_ + lg * 8;
#pragma unroll
    for (int kk = 0; kk < 4; kk++) af[kk] = ld8f_bf(xrow + kk * 32);

    unsigned short* op = Pre0 + ((size_t)t * B_ + bc * 16 + lr) * H_;

#pragma unroll
    for (int i = 0; i < 4; i++) {
        const int n0 = (w + 4 * i) * 16;
        const float* wrow = Wx0 + (size_t)(n0 + lr) * DIN_ + lg * 8;
        bf16x8 bfr[4];
#pragma unroll
        for (int kk = 0; kk < 4; kk++) bfr[kk] = ld8f_bf(wrow + kk * 32);
        float4 bv = *(const float4*)&b0[n0 + lg * 4];
        f32x4 acc = { bv.x, bv.y, bv.z, bv.w };
#pragma unroll
        for (int kk = 0; kk < 4; kk++)
            acc = __builtin_amdgcn_mfma_f32_16x16x32_bf16(bfr[kk], af[kk], acc, 0, 0, 0);
        u32x2 pk;
        pk[0] = cvt_pk_bf16(acc[0], acc[1]);
        pk[1] = cvt_pk_bf16(acc[2], acc[3]);
        *(u32x2*)&op[n0 + lg * 4] = pk;
    }
}

// -------- kernel 2: sequential scan. 64 blocks x ONE batch row; 8 waves x 32 n.
// M=1 => every lane-group-of-16 reads the SAME state chunk from LDS: reads are
// hardware broadcasts (64 unique bytes per ds_read_b128), zero bank conflicts,
// no swizzle. State writes/global stores predicated to lane lr==0.
// Weights register-resident in arch VGPRs (asm "v"), 2 waves/SIMD, 1 barrier/step.
__global__ __launch_bounds__(512, 2) void k_scan(const float* __restrict__ h0in,
                                                 const float* __restrict__ Wh0,
                                                 const float* __restrict__ Wx1,
                                                 const float* __restrict__ Wh1,
                                                 const float* __restrict__ b1,
                                                 const unsigned short* __restrict__ Pre0,
                                                 unsigned short* __restrict__ H1) {
    const int b   = blockIdx.x;            // one batch row per block
    const int tid = threadIdx.x;
    const int w   = tid >> 6, l = tid & 63;
    const int lr  = l & 15, lg = l >> 4;
    const int n0  = w * 32;

    __shared__ __align__(16) unsigned short h0s[2][256];
    __shared__ __align__(16) unsigned short h1s[2][256];

    // weight fragments: lane = W[n = n0+u*16+lr][k = kk*32+lg*8 .. +7]
    bf16x8 wh0f[2][8], wx1f[2][8], wh1f[2][8];
#pragma unroll
    for (int u = 0; u < 2; u++) {
        const int n = n0 + u * 16 + lr;
#pragma unroll
        for (int kk = 0; kk < 8; kk++) {
            const int k0 = kk * 32 + lg * 8;
            wh0f[u][kk] = ld8f_bf(Wh0 + (size_t)n * H_ + k0);
            wx1f[u][kk] = ld8f_bf(Wx1 + (size_t)n * H_ + k0);
            wh1f[u][kk] = ld8f_bf(Wh1 + (size_t)n * H_ + k0);
        }
    }
    float4 b1q0 = *(const float4*)&b1[n0 + lg * 4];
    float4 b1q1 = *(const float4*)&b1[n0 + 16 + lg * 4];

    // init state (linear, no swizzle)
    if (tid < 256) {
        h0s[0][tid] = f2bf(h0in[(size_t)b * H_ + tid]);
        h1s[0][tid] = f2bf(h0in[(size_t)(B_ + b) * H_ + tid]);
    }

    // Pre0 / H1 pointers: (batch b, n = n0+u*16+lg*4 .. +3); uniform across lr
    const unsigned short* prep = Pre0 + (size_t)b * H_ + n0 + lg * 4;
    unsigned short* h1p = H1 + (size_t)b * H_ + n0 + lg * 4;
    u32x2 pv0 = *(const u32x2*)prep;
    u32x2 pv1 = *(const u32x2*)(prep + 16);
    prep += B_ * H_;

    __syncthreads();

    int cur = 0;
    for (int t = 0; t < T_; t++) {
        const int nxt = cur ^ 1;
        // ---- layer 0: h0n^T = Wh0 . h0^T + Pre0^T ; 4 chains (2 n-tiles x 2 k-halves)
        f32x4 a00, a01, a10, a11;
        a00[0] = bfbits_lo(pv0[0]); a00[1] = bfbits_hi(pv0[0]);
        a00[2] = bfbits_lo(pv0[1]); a00[3] = bfbits_hi(pv0[1]);
        a10[0] = bfbits_lo(pv1[0]); a10[1] = bfbits_hi(pv1[0]);
        a10[2] = bfbits_lo(pv1[1]); a10[3] = bfbits_hi(pv1[1]);
        a01 = (f32x4){0.0f, 0.0f, 0.0f, 0.0f};
        a11 = (f32x4){0.0f, 0.0f, 0.0f, 0.0f};
        // prefetch next step's Pre0 (tail over-read lands in H1 region, harmless)
        pv0 = *(const u32x2*)prep;
        pv1 = *(const u32x2*)(prep + 16);
        prep += B_ * H_;
#pragma unroll
        for (int kk = 0; kk < 4; kk++) {
            bf16x8 s0 = __builtin_bit_cast(bf16x8, *(const u16x8*)&h0s[cur][kk * 32 + lg * 8]);
            bf16x8 s1 = __builtin_bit_cast(bf16x8, *(const u16x8*)&h0s[cur][128 + kk * 32 + lg * 8]);
            if (kk == 0) {
                MFMA_FIRST(a00, wh0f[0][0], s0);
                MFMA_FIRST(a10, wh0f[1][0], s0);
                MFMA_FIRST(a01, wh0f[0][4], s1);
                MFMA_FIRST(a11, wh0f[1][4], s1);
            } else if (kk < 3) {
                MFMA_MID(a00, wh0f[0][kk], s0);
                MFMA_MID(a10, wh0f[1][kk], s0);
                MFMA_MID(a01, wh0f[0][kk + 4], s1);
                MFMA_MID(a11, wh0f[1][kk + 4], s1);
            } else {
                a00 = __builtin_amdgcn_mfma_f32_16x16x32_bf16(wh0f[0][3], s0, a00, 0, 0, 0);
                a10 = __builtin_amdgcn_mfma_f32_16x16x32_bf16(wh0f[1][3], s0, a10, 0, 0, 0);
                a01 = __builtin_amdgcn_mfma_f32_16x16x32_bf16(wh0f[0][7], s1, a01, 0, 0, 0);
                a11 = __builtin_amdgcn_mfma_f32_16x16x32_bf16(wh0f[1][7], s1, a11, 0, 0, 0);
            }
        }
        f32x4 h0a = a00 + a01, h0b = a10 + a11;
        u32x2 pk0, pk1;
        pk0[0] = cvt_pk_bf16(tanh_fast(h0a[0]), tanh_fast(h0a[1]));
        pk0[1] = cvt_pk_bf16(tanh_fast(h0a[2]), tanh_fast(h0a[3]));
        pk1[0] = cvt_pk_bf16(tanh_fast(h0b[0]), tanh_fast(h0b[1]));
        pk1[1] = cvt_pk_bf16(tanh_fast(h0b[2]), tanh_fast(h0b[3]));
        if (lr == 0) {
            *(u32x2*)&h0s[nxt][n0 + lg * 4] = pk0;
            *(u32x2*)&h0s[nxt][n0 + 16 + lg * 4] = pk1;
        }

        __syncthreads();   // single barrier per step (other pairs ordered by next one)

        // ---- layer 1: h1n^T = Wx1 . h0n^T + Wh1 . h1^T + b1 ; 4 chains
        f32x4 dA0 = { b1q0.x, b1q0.y, b1q0.z, b1q0.w };
        f32x4 dA1 = { b1q1.x, b1q1.y, b1q1.z, b1q1.w };
        f32x4 dB0 = (f32x4){0.0f, 0.0f, 0.0f, 0.0f};
        f32x4 dB1 = (f32x4){0.0f, 0.0f, 0.0f, 0.0f};
#pragma unroll
        for (int kk = 0; kk < 8; kk++) {
            bf16x8 s0 = __builtin_bit_cast(bf16x8, *(const u16x8*)&h0s[nxt][kk * 32 + lg * 8]);
            bf16x8 s1 = __builtin_bit_cast(bf16x8, *(const u16x8*)&h1s[cur][kk * 32 + lg * 8]);
            if (kk == 0) {
                MFMA_FIRST(dA0, wx1f[0][0], s0);
                MFMA_FIRST(dA1, wx1f[1][0], s0);
                MFMA_FIRST(dB0, wh1f[0][0], s1);
                MFMA_FIRST(dB1, wh1f[1][0], s1);
            } else if (kk < 7) {
                MFMA_MID(dA0, wx1f[0][kk], s0);
                MFMA_MID(dA1, wx1f[1][kk], s0);
                MFMA_MID(dB0, wh1f[0][kk], s1);
                MFMA_MID(dB1, wh1f[1][kk], s1);
            } else {
                dA0 = __builtin_amdgcn_mfma_f32_16x16x32_bf16(wx1f[0][7], s0, dA0, 0, 0, 0);
                dA1 = __builtin_amdgcn_mfma_f32_16x16x32_bf16(wx1f[1][7], s0, dA1, 0, 0, 0);
                dB0 = __builtin_amdgcn_mfma_f32_16x16x32_bf16(wh1f[0][7], s1, dB0, 0, 0, 0);
                dB1 = __builtin_amdgcn_mfma_f32_16x16x32_bf16(wh1f[1][7], s1, dB1, 0, 0, 0);
            }
        }
        f32x4 h1a = dA0 + dB0, h1b = dA1 + dB1;
        pk0[0] = cvt_pk_bf16(tanh_fast(h1a[0]), tanh_fast(h1a[1]));
        pk0[1] = cvt_pk_bf16(tanh_fast(h1a[2]), tanh_fast(h1a[3]));
        pk1[0] = cvt_pk_bf16(tanh_fast(h1b[0]), tanh_fast(h1b[1]));
        pk1[1] = cvt_pk_bf16(tanh_fast(h1b[2]), tanh_fast(h1b[3]));
        if (lr == 0) {
            *(u32x2*)&h1s[nxt][n0 + lg * 4] = pk0;
            *(u32x2*)&h1s[nxt][n0 + 16 + lg * 4] = pk1;
            *(u32x2*)h1p        = pk0;
            *(u32x2*)(h1p + 16) = pk1;
        }
        h1p += B_ * H_;

        cur = nxt;
    }
}

// -------- kernel 3 (swapped): Y[b][t][d] = bout[d] + sum_k H1[t][b][k]*Wout[d][k]
__global__ __launch_bounds__(256) void k_out(const unsigned short* __restrict__ H1,
                                             const float* __restrict__ Wout,
                                             const float* __restrict__ bout,
                                             float* __restrict__ out) {
    const int t  = blockIdx.x;
    const int bc = blockIdx.y;
    const int w  = threadIdx.x >> 6;
    const int l  = threadIdx.x & 63;
    const int lr = l & 15, lg = l >> 4;

    bf16x8 af[8];
    const unsigned short* hrow = H1 + ((size_t)t * B_ + bc * 16 + lr) * H_ + lg * 8;
#pragma unroll
    for (int kk = 0; kk < 8; kk++)
        af[kk] = __builtin_bit_cast(bf16x8, *(const u16x8*)(hrow + kk * 32));

#pragma unroll
    for (int i = 0; i < 2; i++) {
        const int n0 = (w + 4 * i) * 16;
        const float* wrow = Wout + (size_t)(n0 + lr) * H_ + lg * 8;
        float4 bv = *(const float4*)&bout[n0 + lg * 4];
        f32x4 acc = { bv.x, bv.y, bv.z, bv.w };
#pragma unroll
        for (int kk = 0; kk < 8; kk++) {
            bf16x8 bfr = ld8f_bf(wrow + kk * 32);
            acc = __builtin_amdgcn_mfma_f32_16x16x32_bf16(bfr, af[kk], acc, 0, 0, 0);
        }
        *(f32x4*)&out[((size_t)(bc * 16 + lr) * T_ + t) * DOUT_ + n0 + lg * 4] = acc;
    }
}

extern "C" void kernel_launch(void* const* d_in, const int* in_sizes, int n_in,
                              void* d_out, int out_size, void* d_ws, size_t ws_size,
                              hipStream_t stream) {
    const float* x    = (const float*)d_in[0];
    const float* h0   = (const float*)d_in[1];
    const float* Wx0  = (const float*)d_in[2];
    const float* Wh0  = (const float*)d_in[3];
    const float* b0   = (const float*)d_in[4];
    const float* Wx1  = (const float*)d_in[5];
    const float* Wh1  = (const float*)d_in[6];
    const float* b1   = (const float*)d_in[7];
    const float* Wout = (const float*)d_in[8];
    const float* bout = (const float*)d_in[9];
    float* out = (float*)d_out;

    unsigned short* Pre0 = (unsigned short*)d_ws;
    unsigned short* H1   = Pre0 + (size_t)T_ * B_ * H_;

    k_pre<<<dim3(T_, B_ / 16), 256, 0, stream>>>(x, Wx0, b0, Pre0);
    k_scan<<<dim3(B_), 512, 0, stream>>>(h0, Wh0, Wx1, Wh1, b1, Pre0, H1);
    k_out<<<dim3(T_, B_ / 16), 256, 0, stream>>>(H1, Wout, bout, out);
}